// Round 1
// baseline (125.780 us; speedup 1.0000x reference)
//
#include <hip/hip_runtime.h>

// GaussianDynamics recurrent cell as a parallel affine scan.
// x_t = S_t x_{t-1} + o_t,  S_t = I + (A - xic_t C) dt,  o_t = xic_t dy_t
// out_t = C x_{t-1} dt  (uses pre-update state)
//
// One block per batch row (B=16384 blocks x 256 threads).
// Each thread owns SPT=4 consecutive timesteps:
//   load -> compose local affine -> wave shfl scan -> LDS inter-wave fixup
//   -> replay from exclusive-scan start state -> vectorized stores.
// Traffic: read inputs once (393 MB), write outputs once (131 MB). Memory-bound.

constexpr int BATCH = 16384;
constexpr int TLEN  = 1000;
constexpr int TPB   = 256;
constexpr int SPT   = 4;   // TPB*SPT = 1024 >= TLEN (threads 250..255 idle/identity)

__global__ __launch_bounds__(TPB) void gd_scan_kernel(
    const float* __restrict__ xicovs,  // [B,T,2,2]
    const float* __restrict__ dyv,     // [B,T,2]
    const float* __restrict__ cA,      // [2,2]
    const float* __restrict__ Cm,      // [2,2]
    const float* __restrict__ x0,      // [B,2]
    const float* __restrict__ dtp,     // [1]
    float* __restrict__ out)           // [B,T,2] then [B,2]
{
    const int b   = blockIdx.x;
    const int tid = threadIdx.x;
    const int lane = tid & 63;
    const int wv   = tid >> 6;

    const float dts = dtp[0];
    const float C00 = Cm[0], C01 = Cm[1], C10 = Cm[2], C11 = Cm[3];
    const float A00 = cA[0], A01 = cA[1], A10 = cA[2], A11 = cA[3];

    const int t0 = tid * SPT;

    // ---- load this thread's 4 timesteps (coalesced float4 / float2) ----
    float4 xc[SPT];
    float2 dv[SPT];
    const float4* xp = reinterpret_cast<const float4*>(xicovs + (size_t)b * TLEN * 4);
    const float2* dp = reinterpret_cast<const float2*>(dyv    + (size_t)b * TLEN * 2);
#pragma unroll
    for (int s = 0; s < SPT; ++s) {
        const int t = t0 + s;
        if (t < TLEN) { xc[s] = xp[t]; dv[s] = dp[t]; }
        else          { xc[s] = make_float4(0.f,0.f,0.f,0.f); dv[s] = make_float2(0.f,0.f); }
    }

    // ---- compose thread-local affine transform over its steps (time order) ----
    float M00 = 1.f, M01 = 0.f, M10 = 0.f, M11 = 1.f, c0 = 0.f, c1 = 0.f;
#pragma unroll
    for (int s = 0; s < SPT; ++s) {
        const int t = t0 + s;
        if (t < TLEN) {
            const float xi00 = xc[s].x, xi01 = xc[s].y, xi10 = xc[s].z, xi11 = xc[s].w;
            const float Am00 = A00 - (xi00 * C00 + xi01 * C10);
            const float Am01 = A01 - (xi00 * C01 + xi01 * C11);
            const float Am10 = A10 - (xi10 * C00 + xi11 * C10);
            const float Am11 = A11 - (xi10 * C01 + xi11 * C11);
            const float S00 = 1.f + Am00 * dts, S01 = Am01 * dts;
            const float S10 = Am10 * dts,       S11 = 1.f + Am11 * dts;
            const float o0 = xi00 * dv[s].x + xi01 * dv[s].y;
            const float o1 = xi10 * dv[s].x + xi11 * dv[s].y;
            // new = S o old
            const float n00 = S00 * M00 + S01 * M10;
            const float n01 = S00 * M01 + S01 * M11;
            const float n10 = S10 * M00 + S11 * M10;
            const float n11 = S10 * M01 + S11 * M11;
            const float nc0 = S00 * c0 + S01 * c1 + o0;
            const float nc1 = S10 * c0 + S11 * c1 + o1;
            M00 = n00; M01 = n01; M10 = n10; M11 = n11; c0 = nc0; c1 = nc1;
        }
    }

    // ---- wave-level inclusive scan (Hillis-Steele over 64 lanes) ----
#pragma unroll
    for (int off = 1; off < 64; off <<= 1) {
        const float m00 = __shfl_up(M00, off);
        const float m01 = __shfl_up(M01, off);
        const float m10 = __shfl_up(M10, off);
        const float m11 = __shfl_up(M11, off);
        const float lc0 = __shfl_up(c0,  off);
        const float lc1 = __shfl_up(c1,  off);
        if (lane >= off) {
            const float n00 = M00 * m00 + M01 * m10;
            const float n01 = M00 * m01 + M01 * m11;
            const float n10 = M10 * m00 + M11 * m10;
            const float n11 = M10 * m01 + M11 * m11;
            const float nc0 = M00 * lc0 + M01 * lc1 + c0;
            const float nc1 = M10 * lc0 + M11 * lc1 + c1;
            M00 = n00; M01 = n01; M10 = n10; M11 = n11; c0 = nc0; c1 = nc1;
        }
    }

    // ---- inter-wave fixup: lane 63 of each wave publishes its inclusive total ----
    __shared__ float wsum[TPB / 64][6];
    if (lane == 63) {
        wsum[wv][0] = M00; wsum[wv][1] = M01; wsum[wv][2] = M10; wsum[wv][3] = M11;
        wsum[wv][4] = c0;  wsum[wv][5] = c1;
    }
    __syncthreads();

    float P00 = 1.f, P01 = 0.f, P10 = 0.f, P11 = 1.f, Pc0 = 0.f, Pc1 = 0.f;
    for (int w = 0; w < wv; ++w) {
        const float w00 = wsum[w][0], w01 = wsum[w][1], w10 = wsum[w][2], w11 = wsum[w][3];
        const float wc0 = wsum[w][4], wc1 = wsum[w][5];
        // P = T_w o P
        const float n00 = w00 * P00 + w01 * P10;
        const float n01 = w00 * P01 + w01 * P11;
        const float n10 = w10 * P00 + w11 * P10;
        const float n11 = w10 * P01 + w11 * P11;
        const float nc0 = w00 * Pc0 + w01 * Pc1 + wc0;
        const float nc1 = w10 * Pc0 + w11 * Pc1 + wc1;
        P00 = n00; P01 = n01; P10 = n10; P11 = n11; Pc0 = nc0; Pc1 = nc1;
    }

    // ---- within-wave exclusive = inclusive of lane-1 (identity for lane 0) ----
    float e00 = __shfl_up(M00, 1), e01 = __shfl_up(M01, 1);
    float e10 = __shfl_up(M10, 1), e11 = __shfl_up(M11, 1);
    float ec0 = __shfl_up(c0, 1),  ec1 = __shfl_up(c1, 1);
    if (lane == 0) { e00 = 1.f; e01 = 0.f; e10 = 0.f; e11 = 1.f; ec0 = 0.f; ec1 = 0.f; }

    // E = e o P  (global exclusive transform for this thread)
    const float E00 = e00 * P00 + e01 * P10;
    const float E01 = e00 * P01 + e01 * P11;
    const float E10 = e10 * P00 + e11 * P10;
    const float E11 = e10 * P01 + e11 * P11;
    const float Ec0 = e00 * Pc0 + e01 * Pc1 + ec0;
    const float Ec1 = e10 * Pc0 + e11 * Pc1 + ec1;

    // start state for this thread's chunk: x_{t0-1} = E(x0)
    const float xa = x0[2 * b], xb = x0[2 * b + 1];
    float xq0 = E00 * xa + E01 * xb + Ec0;
    float xq1 = E10 * xa + E11 * xb + Ec1;

    // ---- replay the chunk, emitting outputs ----
    float2 ov[SPT];
#pragma unroll
    for (int s = 0; s < SPT; ++s) {
        const int t = t0 + s;
        if (t < TLEN) {
            const float o0 = (C00 * xq0 + C01 * xq1) * dts;
            const float o1 = (C10 * xq0 + C11 * xq1) * dts;
            ov[s] = make_float2(o0, o1);
            const float xi00 = xc[s].x, xi01 = xc[s].y, xi10 = xc[s].z, xi11 = xc[s].w;
            const float Am00 = A00 - (xi00 * C00 + xi01 * C10);
            const float Am01 = A01 - (xi00 * C01 + xi01 * C11);
            const float Am10 = A10 - (xi10 * C00 + xi11 * C10);
            const float Am11 = A11 - (xi10 * C01 + xi11 * C11);
            const float d0 = xi00 * dv[s].x + xi01 * dv[s].y;
            const float d1 = xi10 * dv[s].x + xi11 * dv[s].y;
            const float nx0 = xq0 + (Am00 * xq0 + Am01 * xq1) * dts + d0;
            const float nx1 = xq1 + (Am10 * xq0 + Am11 * xq1) * dts + d1;
            xq0 = nx0; xq1 = nx1;
        }
    }

    float* ob = out + (size_t)b * TLEN * 2 + (size_t)t0 * 2;
    if (t0 + SPT <= TLEN) {
        reinterpret_cast<float4*>(ob)[0] = make_float4(ov[0].x, ov[0].y, ov[1].x, ov[1].y);
        reinterpret_cast<float4*>(ob)[1] = make_float4(ov[2].x, ov[2].y, ov[3].x, ov[3].y);
    } else {
        for (int s = 0; s < SPT; ++s)
            if (t0 + s < TLEN) reinterpret_cast<float2*>(ob)[s] = ov[s];
    }

    // thread owning the last timestep writes the final state
    if (t0 < TLEN && t0 + SPT >= TLEN) {
        float* xf = out + (size_t)BATCH * TLEN * 2 + 2 * b;
        xf[0] = xq0; xf[1] = xq1;
    }
}

extern "C" void kernel_launch(void* const* d_in, const int* in_sizes, int n_in,
                              void* d_out, int out_size, void* d_ws, size_t ws_size,
                              hipStream_t stream) {
    const float* xicovs = (const float*)d_in[0];
    const float* dyv    = (const float*)d_in[1];
    const float* cA     = (const float*)d_in[2];
    const float* Cm     = (const float*)d_in[3];
    const float* x0     = (const float*)d_in[4];
    const float* dtp    = (const float*)d_in[5];
    float* out = (float*)d_out;

    gd_scan_kernel<<<BATCH, TPB, 0, stream>>>(xicovs, dyv, cA, Cm, x0, dtp, out);
}

// Round 3
// 108.496 us; speedup vs baseline: 1.1593x; 1.1593x over previous
//
#include <hip/hip_runtime.h>

// GaussianDynamics recurrent cell as a parallel affine scan.
// x_t = S_t x_{t-1} + o_t,  S_t = I + (A - xic_t C) dt,  o_t = xic_t dy_t
// out_t = C x_{t-1} dt  (pre-update state)
//
// One block per batch row (B=16384 blocks x 256 threads), SPT=4 steps/thread.
// R1/R2 changes vs R0:
//  - LDS staging of the whole row (SoA layout): global loads are contiguous
//    float4/float2 per lane (R0 had 64B lane stride -> 4x VMEM request rate).
//  - SoA in LDS => each thread's chunk read is a contiguous ds_read_b128,
//    bank-conflict-free.
//  - __launch_bounds__(256,6) (LDS caps us at 6 blocks/CU anyway).
//  - nontemporal output stores via clang ext_vector types (HIP float4 is a
//    struct and rejected by __builtin_nontemporal_store — R2 fix).

constexpr int BATCH = 16384;
constexpr int TLEN  = 1000;
constexpr int TPB   = 256;
constexpr int SPT   = 4;     // TPB*SPT = 1024 >= TLEN
constexpr int TPAD  = 1024;  // padded LDS row length

typedef float vfloat4 __attribute__((ext_vector_type(4)));
typedef float vfloat2 __attribute__((ext_vector_type(2)));

__global__ __launch_bounds__(TPB, 6) void gd_scan_kernel(
    const float* __restrict__ xicovs,  // [B,T,2,2]
    const float* __restrict__ dyv,     // [B,T,2]
    const float* __restrict__ cA,      // [2,2]
    const float* __restrict__ Cm,      // [2,2]
    const float* __restrict__ x0,      // [B,2]
    const float* __restrict__ dtp,     // [1]
    float* __restrict__ out)           // [B,T,2] then [B,2]
{
    __shared__ float s_xi00[TPAD], s_xi01[TPAD], s_xi10[TPAD], s_xi11[TPAD];
    __shared__ float s_dy0[TPAD], s_dy1[TPAD];
    __shared__ float wsum[TPB / 64][6];

    const int b    = blockIdx.x;
    const int tid  = threadIdx.x;
    const int lane = tid & 63;
    const int wv   = tid >> 6;

    // ---- stage row into LDS, SoA transpose, fully coalesced global loads ----
    {
        const vfloat4* gx = reinterpret_cast<const vfloat4*>(xicovs + (size_t)b * TLEN * 4);
        for (int i = tid; i < TLEN; i += TPB) {
            const vfloat4 v = gx[i];
            s_xi00[i] = v.x; s_xi01[i] = v.y; s_xi10[i] = v.z; s_xi11[i] = v.w;
        }
        const vfloat2* gd = reinterpret_cast<const vfloat2*>(dyv + (size_t)b * TLEN * 2);
        for (int i = tid; i < TLEN; i += TPB) {
            const vfloat2 v = gd[i];
            s_dy0[i] = v.x; s_dy1[i] = v.y;
        }
    }

    const float dts = dtp[0];
    const float C00 = Cm[0], C01 = Cm[1], C10 = Cm[2], C11 = Cm[3];
    const float A00 = cA[0], A01 = cA[1], A10 = cA[2], A11 = cA[3];

    __syncthreads();

    const int t0 = tid * SPT;

    // ---- read this thread's 4 steps: contiguous 16B LDS reads, SoA ----
    const vfloat4 q00 = *reinterpret_cast<const vfloat4*>(&s_xi00[t0]);
    const vfloat4 q01 = *reinterpret_cast<const vfloat4*>(&s_xi01[t0]);
    const vfloat4 q10 = *reinterpret_cast<const vfloat4*>(&s_xi10[t0]);
    const vfloat4 q11 = *reinterpret_cast<const vfloat4*>(&s_xi11[t0]);
    const vfloat4 qd0 = *reinterpret_cast<const vfloat4*>(&s_dy0[t0]);
    const vfloat4 qd1 = *reinterpret_cast<const vfloat4*>(&s_dy1[t0]);

    const float xi00s[SPT] = {q00.x, q00.y, q00.z, q00.w};
    const float xi01s[SPT] = {q01.x, q01.y, q01.z, q01.w};
    const float xi10s[SPT] = {q10.x, q10.y, q10.z, q10.w};
    const float xi11s[SPT] = {q11.x, q11.y, q11.z, q11.w};
    const float dy0s[SPT]  = {qd0.x, qd0.y, qd0.z, qd0.w};
    const float dy1s[SPT]  = {qd1.x, qd1.y, qd1.z, qd1.w};

    // ---- per-step affine (S,o), composed in time order ----
    float S00s[SPT], S01s[SPT], S10s[SPT], S11s[SPT], o0s[SPT], o1s[SPT];
    float M00 = 1.f, M01 = 0.f, M10 = 0.f, M11 = 1.f, c0 = 0.f, c1 = 0.f;
#pragma unroll
    for (int s = 0; s < SPT; ++s) {
        const int t = t0 + s;
        const float xi00 = xi00s[s], xi01 = xi01s[s], xi10 = xi10s[s], xi11 = xi11s[s];
        const float Am00 = A00 - (xi00 * C00 + xi01 * C10);
        const float Am01 = A01 - (xi00 * C01 + xi01 * C11);
        const float Am10 = A10 - (xi10 * C00 + xi11 * C10);
        const float Am11 = A11 - (xi10 * C01 + xi11 * C11);
        float S00 = 1.f + Am00 * dts, S01 = Am01 * dts;
        float S10 = Am10 * dts,       S11 = 1.f + Am11 * dts;
        float o0 = xi00 * dy0s[s] + xi01 * dy1s[s];
        float o1 = xi10 * dy0s[s] + xi11 * dy1s[s];
        if (t >= TLEN) { S00 = 1.f; S01 = 0.f; S10 = 0.f; S11 = 1.f; o0 = 0.f; o1 = 0.f; }
        S00s[s] = S00; S01s[s] = S01; S10s[s] = S10; S11s[s] = S11; o0s[s] = o0; o1s[s] = o1;
        // M,c = S o (M,c)
        const float n00 = S00 * M00 + S01 * M10;
        const float n01 = S00 * M01 + S01 * M11;
        const float n10 = S10 * M00 + S11 * M10;
        const float n11 = S10 * M01 + S11 * M11;
        const float nc0 = S00 * c0 + S01 * c1 + o0;
        const float nc1 = S10 * c0 + S11 * c1 + o1;
        M00 = n00; M01 = n01; M10 = n10; M11 = n11; c0 = nc0; c1 = nc1;
    }

    // ---- wave-level inclusive scan (Hillis-Steele over 64 lanes) ----
#pragma unroll
    for (int off = 1; off < 64; off <<= 1) {
        const float m00 = __shfl_up(M00, off);
        const float m01 = __shfl_up(M01, off);
        const float m10 = __shfl_up(M10, off);
        const float m11 = __shfl_up(M11, off);
        const float lc0 = __shfl_up(c0,  off);
        const float lc1 = __shfl_up(c1,  off);
        if (lane >= off) {
            const float n00 = M00 * m00 + M01 * m10;
            const float n01 = M00 * m01 + M01 * m11;
            const float n10 = M10 * m00 + M11 * m10;
            const float n11 = M10 * m01 + M11 * m11;
            const float nc0 = M00 * lc0 + M01 * lc1 + c0;
            const float nc1 = M10 * lc0 + M11 * lc1 + c1;
            M00 = n00; M01 = n01; M10 = n10; M11 = n11; c0 = nc0; c1 = nc1;
        }
    }

    // ---- inter-wave fixup ----
    if (lane == 63) {
        wsum[wv][0] = M00; wsum[wv][1] = M01; wsum[wv][2] = M10; wsum[wv][3] = M11;
        wsum[wv][4] = c0;  wsum[wv][5] = c1;
    }
    __syncthreads();

    float P00 = 1.f, P01 = 0.f, P10 = 0.f, P11 = 1.f, Pc0 = 0.f, Pc1 = 0.f;
    for (int w = 0; w < wv; ++w) {
        const float w00 = wsum[w][0], w01 = wsum[w][1], w10 = wsum[w][2], w11 = wsum[w][3];
        const float wc0 = wsum[w][4], wc1 = wsum[w][5];
        const float n00 = w00 * P00 + w01 * P10;
        const float n01 = w00 * P01 + w01 * P11;
        const float n10 = w10 * P00 + w11 * P10;
        const float n11 = w10 * P01 + w11 * P11;
        const float nc0 = w00 * Pc0 + w01 * Pc1 + wc0;
        const float nc1 = w10 * Pc0 + w11 * Pc1 + wc1;
        P00 = n00; P01 = n01; P10 = n10; P11 = n11; Pc0 = nc0; Pc1 = nc1;
    }

    // ---- within-wave exclusive = inclusive of lane-1 ----
    float e00 = __shfl_up(M00, 1), e01 = __shfl_up(M01, 1);
    float e10 = __shfl_up(M10, 1), e11 = __shfl_up(M11, 1);
    float ec0 = __shfl_up(c0, 1),  ec1 = __shfl_up(c1, 1);
    if (lane == 0) { e00 = 1.f; e01 = 0.f; e10 = 0.f; e11 = 1.f; ec0 = 0.f; ec1 = 0.f; }

    // E = e o P
    const float E00 = e00 * P00 + e01 * P10;
    const float E01 = e00 * P01 + e01 * P11;
    const float E10 = e10 * P00 + e11 * P10;
    const float E11 = e10 * P01 + e11 * P11;
    const float Ec0 = e00 * Pc0 + e01 * Pc1 + ec0;
    const float Ec1 = e10 * Pc0 + e11 * Pc1 + ec1;

    // start state for this chunk: x_{t0-1} = E(x0)
    const float xa = x0[2 * b], xb = x0[2 * b + 1];
    float xq0 = E00 * xa + E01 * xb + Ec0;
    float xq1 = E10 * xa + E11 * xb + Ec1;

    // ---- replay chunk from (S,o) in registers, emit outputs ----
    float o0v[SPT], o1v[SPT];
#pragma unroll
    for (int s = 0; s < SPT; ++s) {
        o0v[s] = (C00 * xq0 + C01 * xq1) * dts;
        o1v[s] = (C10 * xq0 + C11 * xq1) * dts;
        const float nx0 = S00s[s] * xq0 + S01s[s] * xq1 + o0s[s];
        const float nx1 = S10s[s] * xq0 + S11s[s] * xq1 + o1s[s];
        xq0 = nx0; xq1 = nx1;
    }

    float* ob = out + (size_t)b * TLEN * 2 + (size_t)t0 * 2;
    if (t0 + SPT <= TLEN) {
        vfloat4 w0 = {o0v[0], o1v[0], o0v[1], o1v[1]};
        vfloat4 w1 = {o0v[2], o1v[2], o0v[3], o1v[3]};
        __builtin_nontemporal_store(w0, reinterpret_cast<vfloat4*>(ob));
        __builtin_nontemporal_store(w1, reinterpret_cast<vfloat4*>(ob) + 1);
    } else {
        for (int s = 0; s < SPT; ++s)
            if (t0 + s < TLEN) {
                vfloat2 w = {o0v[s], o1v[s]};
                __builtin_nontemporal_store(w, reinterpret_cast<vfloat2*>(ob) + s);
            }
    }

    // thread owning the last timestep writes the final state
    if (t0 < TLEN && t0 + SPT >= TLEN) {
        float* xf = out + (size_t)BATCH * TLEN * 2 + 2 * b;
        xf[0] = xq0; xf[1] = xq1;
    }
}

extern "C" void kernel_launch(void* const* d_in, const int* in_sizes, int n_in,
                              void* d_out, int out_size, void* d_ws, size_t ws_size,
                              hipStream_t stream) {
    const float* xicovs = (const float*)d_in[0];
    const float* dyv    = (const float*)d_in[1];
    const float* cA     = (const float*)d_in[2];
    const float* Cm     = (const float*)d_in[3];
    const float* x0     = (const float*)d_in[4];
    const float* dtp    = (const float*)d_in[5];
    float* out = (float*)d_out;

    gd_scan_kernel<<<BATCH, TPB, 0, stream>>>(xicovs, dyv, cA, Cm, x0, dtp, out);
}